// Round 7
// baseline (4972.807 us; speedup 1.0000x reference)
//
#include <hip/hip_runtime.h>
#include <cmath>

#define SEQ 512
#define BATCH 2048
#define DIM 64
#define HID 128
#define SB (BATCH * DIM)   // x stride per timestep (floats)

// Round-15: dual-batch blocks. r14 post-mortem: redundant tail on all waves
// HURT (1660->1760; VALU issue was a co-bottleneck at 54% busy) -> reverted.
// r13's residual gap is ~35% barrier-parked serial latency per step that 1.8
// resident blocks/CU can't fill. Register wall blocks deeper k-splits, so:
// amortize instead. Each block processes TWO batch elements with the SAME
// pinned weights (weights are batch-invariant):
//   - 96 FMA/thread-step (2 batches x 48), still zero redundancy
//   - barriers per batch-step HALVED (2 barriers now cover 2 batch elements)
//   - tail: kq0 waves own batch-0, kq1 waves own batch-1 (4/8 waves active in
//     Y vs 2/8 in r13; two independent LDS-latency + exp chains overlap)
//   - grid 1024 blocks; register cost +~10 -> ~81 demand < the allocator's
//     empirical 84 target (r10-r12 saga), so no spill expected.
// Everything else is r13: 4-way k-split, wave-uniform ds_read_b128 operand
// broadcast, GEMM1(t+1) under GEMM2(t), 2 lgkm-only barriers/step, reg-staged
// x (pairs of 2 steps x 2 batches = 256 floats = 1 float4/lane).

#define R4(M) M(0) M(1) M(2) M(3)
#define R8(M) R4(M) M(4) M(5) M(6) M(7)

#define PIN4(F_) asm volatile("" : "+v"(F_.x), "+v"(F_.y), "+v"(F_.z), "+v"(F_.w));
#define PIN1(F_) asm volatile("" : "+v"(F_));

__device__ __forceinline__ float fast_tanh(float z) {
    // tanh(z) = 1 - 2/(exp(2z)+1); v_exp + v_rcp, exact saturation both ends.
    const float e = __expf(2.0f * z);
    return 1.0f - 2.0f * __builtin_amdgcn_rcpf(e + 1.0f);
}

__global__ __launch_bounds__(512)
__attribute__((amdgpu_waves_per_eu(4, 6)))
void rnn_kernel(const float* __restrict__ x,
                const float* __restrict__ h0,
                const float* __restrict__ W_ih,
                const float* __restrict__ b_ih,
                const float* __restrict__ W_hh,
                const float* __restrict__ b_hh,
                float* __restrict__ out) {
    // xs pair layout: linear idx = s*128 + bb*64 + f  (s = step-in-pair,
    // bb = batch-in-block, f = x float idx). Lane L stages float4 at L*4.
    __shared__ __align__(16) float xs[2][256];       // 2 pair-buffers, 2 KB
    __shared__ __align__(16) float part1[2][4][HID]; // [batch][quarter][j]
    __shared__ __align__(16) float part2[2][4][HID];
    __shared__ __align__(16) float act[2][HID];      // [batch][j] wihx tiles

    const int tid = threadIdx.x;
    const int j = tid & 127;          // hidden index
    const int kq = tid >> 7;          // k-quarter owner 0..3 (wave-uniform)
    const int lane = tid & 63;
    const int b0 = blockIdx.x * 2;    // this block's batch pair

    // ---- pinned weight slices (shared across both batch elements) ----
    const float4* wip = (const float4*)(W_ih + j * DIM + kq * 16);
#define DECL_WI(i) float4 wi##i = wip[i]; PIN4(wi##i)
    R4(DECL_WI)
    const float4* whp = (const float4*)(W_hh + j * HID + kq * 32);
#define DECL_WH(i) float4 wh##i = whp[i]; PIN4(wh##i)
    R8(DECL_WH)

    float bi = b_ih[j];  PIN1(bi)
    float bh = b_hh[j];  PIN1(bh)
    // kq0 threads own batch b0+0's state, kq1 own b0+1's; kq2/3 none.
    float h = (kq < 2) ? h0[(b0 + kq) * HID + j] : 0.0f;

    // ---- x staging: lane L covers step (L>>5), batch ((L>>4)&1),
    //      floats (L&15)*4 .. +4 of the current 2-step pair ----
    const float* xgl = x + (size_t)b0 * DIM + (size_t)(lane >> 5) * SB
                         + (size_t)(((lane >> 4) & 1) * DIM)
                         + (size_t)((lane & 15) * 4);
    float* xldsW = &xs[0][lane * 4];  // buffer stride = 256 floats

    *(float4*)(xldsW)       = *(const float4*)(xgl);                  // pair 0
    *(float4*)(xldsW + 256) = *(const float4*)(xgl + 2 * (size_t)SB); // pair 1
    float4 xr = *(const float4*)(xgl + 4 * (size_t)SB);   // pair 2 in flight
    const float* xnext = xgl + 6 * (size_t)SB;            // pair 3 source

    // ---- prologue: produce act(0) for both batches ----
    float wihx = 0.0f;
    {
        float pP0 = 0.f, pQ0 = 0.f, pP1 = 0.f, pQ1 = 0.f;
        const float* xb = &xs[0][kq * 16];
        const float4* xv0 = (const float4*)(xb);
        const float4* xv1 = (const float4*)(xb + 64);
#define G1N(c) { const float4 u_ = xv0[c]; const float4 v_ = xv1[c]; \
        pP0 += wi##c.x * u_.x; pP0 += wi##c.y * u_.y; \
        pQ0 += wi##c.z * u_.z; pQ0 += wi##c.w * u_.w; \
        pP1 += wi##c.x * v_.x; pP1 += wi##c.y * v_.y; \
        pQ1 += wi##c.z * v_.z; pQ1 += wi##c.w * v_.w; }
        R4(G1N)
        part1[0][kq][j] = pP0 + pQ0;
        part1[1][kq][j] = pP1 + pQ1;
    }
    asm volatile("s_waitcnt lgkmcnt(0)\n\ts_barrier" ::: "memory");
    if (kq < 2) {
        const float* p1 = &part1[kq][0][j];
        wihx = (((p1[0] + p1[128]) + (p1[256] + p1[384])) + bi) * h;
        act[kq][j] = wihx;
    }
    asm volatile("s_waitcnt lgkmcnt(0)\n\ts_barrier" ::: "memory");

#pragma unroll 2
    for (int t = 0; t < SEQ; ++t) {
        // pair boundary (odd t, compile-time under unroll-2): commit the
        // in-flight pair (p+2, covering steps t+3..t+4) and load pair p+3.
        // WAR safe: pair p's last reads (G1N tn=t at step t-1) are sealed by
        // B_odd(t-1)+B_even(t-1). RAW safe: commit drains at B_odd(t), first
        // read is 2 steps later.
        if ((t & 1) == 1) {
            if (t + 3 < SEQ) {
                *(float4*)(xldsW + ((t >> 1) & 1) * 256) = xr; // waits xr vmcnt
                if (t + 5 < SEQ) {
                    xr = *(const float4*)xnext;
                    xnext += 2 * (size_t)SB;
                }
            }
        }

        // ---- X: GEMM2(t) own quarter + GEMM1(t+1) quarter, BOTH batches ----
        float qP0 = 0.f, qQ0 = 0.f, qP1 = 0.f, qQ1 = 0.f;
        const float4* av0 = (const float4*)&act[0][kq * 32];
        const float4* av1 = (const float4*)&act[1][kq * 32];
#define G2P(c) { const float4 u_ = av0[c]; const float4 v_ = av1[c]; \
        qP0 += wh##c.x * u_.x; qP0 += wh##c.y * u_.y; \
        qQ0 += wh##c.z * u_.z; qQ0 += wh##c.w * u_.w; \
        qP1 += wh##c.x * v_.x; qP1 += wh##c.y * v_.y; \
        qQ1 += wh##c.z * v_.z; qQ1 += wh##c.w * v_.w; }
        R8(G2P)

        const int tn = t + 1;
        if (tn < SEQ) {          // GEMM1 is non-recurrent: next step's partials
            float pP0 = 0.f, pQ0 = 0.f, pP1 = 0.f, pQ1 = 0.f;
            const float* xb = &xs[(tn >> 1) & 1][(tn & 1) * 128 + kq * 16];
            const float4* xv0 = (const float4*)(xb);
            const float4* xv1 = (const float4*)(xb + 64);
            R4(G1N)
            part1[0][kq][j] = pP0 + pQ0;
            part1[1][kq][j] = pP1 + pQ1;
        }
        part2[0][kq][j] = qP0 + qQ0;
        part2[1][kq][j] = qP1 + qQ1;
        asm volatile("s_waitcnt lgkmcnt(0)\n\ts_barrier" ::: "memory");  // B_odd

        // ---- Y: kq0 waves run batch-0 tail, kq1 waves batch-1 tail ----
        if (kq < 2) {
            const float* p2 = &part2[kq][0][j];
            const float whh = (((p2[0] + p2[128]) + (p2[256] + p2[384])) + bh) * h;
            h = fast_tanh(wihx + whh);
            if (tn < SEQ) {
                const float* p1 = &part1[kq][0][j];
                wihx = (((p1[0] + p1[128]) + (p1[256] + p1[384])) + bi) * h;
                act[kq][j] = wihx;
            }
        }
        asm volatile("s_waitcnt lgkmcnt(0)\n\ts_barrier" ::: "memory");  // B_even
        // act/part single-buffered is safe: read X(t) / write Y(t) split by
        // B_odd; write Y(t) / read X(t+1) split by B_even.
    }

    if (kq < 2) out[(b0 + kq) * HID + j] = h;
}

extern "C" void kernel_launch(void* const* d_in, const int* in_sizes, int n_in,
                              void* d_out, int out_size, void* d_ws, size_t ws_size,
                              hipStream_t stream) {
    const float* x    = (const float*)d_in[0];
    const float* h0   = (const float*)d_in[1];
    const float* W_ih = (const float*)d_in[2];
    const float* b_ih = (const float*)d_in[3];
    const float* W_hh = (const float*)d_in[4];
    const float* b_hh = (const float*)d_in[5];
    float* out = (float*)d_out;

    dim3 grid(BATCH / 2);   // two batch elements per block
    dim3 block(512);        // 8 waves: (j 0..127) x (k-quarter 0..3)
    rnn_kernel<<<grid, block, 0, stream>>>(x, h0, W_ih, b_ih, W_hh, b_hh, out);
}